// Round 4
// baseline (510.956 us; speedup 1.0000x reference)
//
#include <hip/hip_runtime.h>

// B=8, C=64, H=256, W=256
#define BB 8
#define CC 64
#define HH 256
#define WW 256
#define HW (HH*WW)

typedef __attribute__((ext_vector_type(8))) short bf16x8;
typedef __attribute__((ext_vector_type(4))) float f32x4;

__device__ __forceinline__ int reflect_idx(int v, int n) {
    if (v < 0) v = -v;
    if (v >= n) v = 2*n - 2 - v;
    return v;
}

// f32 -> bf16 (RNE) raw bits
__device__ __forceinline__ short f2bf(float f) {
    union { float f; unsigned u; } x; x.f = f;
    unsigned r = (x.u + 0x7fffu + ((x.u >> 16) & 1u)) >> 16;
    return (short)r;
}

__device__ __forceinline__ unsigned cvt_pk_bf16(float lo, float hi) {
    unsigned r;
    asm("v_cvt_pk_bf16_f32 %0, %1, %2" : "=v"(r) : "v"(lo), "v"(hi));
    return r;
}

__global__ __launch_bounds__(256, 4)
void corr_regB_kernel(const float* __restrict__ hs,
                      const float* __restrict__ refLR,
                      const float* __restrict__ w_first,
                      const float* __restrict__ b_first,
                      const float* __restrict__ w_fuse,
                      const float* __restrict__ b_fuse,
                      float* __restrict__ out)
{
    // s_w: bf16 w_fuse, quad-interleaved k-order: k' = g*32 + q*8 + j,
    //      j<4 -> att col (g*16+q*4+j), j>=4 -> hs col (64+g*16+q*4+j-4)
    __shared__ short s_w[64 * 136];      // 17408 B (row 272B -> conflict-free-profile b128)
    __shared__ float s_p[4][40 * 20];    // 12800 B per-wave p buffers [pos][16ch pad 20]
    __shared__ float s_wf[64 * 10];      // 2560 B: w_first[9] + b_first
                                         // total 32768 B -> 5 blocks/CU

    const int t = threadIdx.x;
    const int wv = t >> 6, lane = t & 63;
    const int cl = lane & 15, kb = lane >> 4;     // pixel-in-strip, channel-quad
    const int pr = cl >> 3, pc = cl & 7;          // pixel row/col within 2x8 strip

    // XCD swizzle: each XCD owns one batch image
    const int d = (int)blockIdx.x;
    const int lid = (d & 7) * 256 + (d >> 3);
    const int bx = lid & 15, by = (lid >> 4) & 15, b = lid >> 8;

    // ---- stage weights ----
    #pragma unroll
    for (int rep = 0; rep < 32; ++rep) {
        int idx = t + rep * 256;                  // m*128 + k'
        int m = idx >> 7, k = idx & 127;
        int g = k >> 5, r = k & 31, q = r >> 3, j = r & 7;
        int col = (j < 4) ? (g*16 + q*4 + j) : (64 + g*16 + q*4 + j - 4);
        s_w[m * 136 + k] = f2bf(w_fuse[m * 128 + col]);
    }
    for (int idx = t; idx < 640; idx += 256) {
        int c = idx / 10, j = idx % 10;
        s_wf[idx] = (j < 9) ? w_first[c*9 + j] : b_first[c];
    }
    __syncthreads();   // only block barrier

    // ---- wave tile: 8x8 pixels, 4 strips of 2x8 ----
    const int wy = (wv >> 1) * 8, wx = (wv & 1) * 8;
    const int y0 = by * 16 + wy, x0 = bx * 16 + wx;
    float* const sp = s_p[wv];

    // owned halo positions (40 = 4 rows x 10 cols): cl, cl+16, cl+32(cl<8)
    const int hr0 = cl / 10,        hc0 = cl % 10;
    const int hr1 = (cl+16) / 10,   hc1 = (cl+16) % 10;
    const int hr2 = (cl+32) / 10,   hc2 = (cl+32) % 10;
    const bool has2 = cl < 8;

    const float* hsb   = hs    + (size_t)b * CC * HW;
    const float* rbase = refLR + (size_t)b * 9 * HW;

    #pragma unroll 1
    for (int nt = 0; nt < 4; ++nt) {
        const int ys = y0 + nt * 2;
        const int gof0 = reflect_idx(ys-1+hr0, HH) * WW + reflect_idx(x0-1+hc0, WW);
        const int gof1 = reflect_idx(ys-1+hr1, HH) * WW + reflect_idx(x0-1+hc1, WW);
        const int gof2 = reflect_idx(ys-1+hr2, HH) * WW + reflect_idx(x0-1+hc2, WW);
        const int gc   = (ys + pr) * WW + (x0 + pc);

        // refLR halo values for this strip (reused across all 4 groups)
        float rin0[9], rin1[9], rin2[9];
        #pragma unroll
        for (int j = 0; j < 9; ++j) {
            rin0[j] = rbase[(size_t)j * HW + gof0];
            rin1[j] = rbase[(size_t)j * HW + gof1];
            rin2[j] = has2 ? rbase[(size_t)j * HW + gof2] : 0.f;
        }

        // prefetch g=0 hs values
        float h0[4], h1[4], h2[4], hcv[4];
        {
            const int cb = kb * 4;
            #pragma unroll
            for (int c4 = 0; c4 < 4; ++c4) {
                const float* hp = hsb + (size_t)(cb + c4) * HW;
                h0[c4] = hp[gof0]; h1[c4] = hp[gof1];
                h2[c4] = has2 ? hp[gof2] : 0.f;
                hcv[c4] = hp[gc];
            }
        }

        f32x4 acc[4];
        #pragma unroll
        for (int mt = 0; mt < 4; ++mt) acc[mt] = (f32x4){0.f, 0.f, 0.f, 0.f};

        #pragma unroll
        for (int g = 0; g < 4; ++g) {
            const int cb = g * 16 + kb * 4;

            // conv (1x1 ref conv + leaky) at owned halo positions, 4 channels
            f32x4 p0, p1, p2;
            float hgate[4];
            #pragma unroll
            for (int c4 = 0; c4 < 4; ++c4) {
                const float* wf = &s_wf[(cb + c4) * 10];
                float v0 = wf[9], v1 = v0, v2 = v0;
                #pragma unroll
                for (int j = 0; j < 9; ++j) {
                    const float w = wf[j];
                    v0 = fmaf(w, rin0[j], v0);
                    v1 = fmaf(w, rin1[j], v1);
                    v2 = fmaf(w, rin2[j], v2);
                }
                v0 = v0 > 0.f ? v0 : 0.1f * v0;
                v1 = v1 > 0.f ? v1 : 0.1f * v1;
                v2 = v2 > 0.f ? v2 : 0.1f * v2;
                p0[c4] = h0[c4] * v0;
                p1[c4] = h1[c4] * v1;
                p2[c4] = h2[c4] * v2;
                hgate[c4] = hcv[c4];
            }
            *(f32x4*)&sp[cl * 20 + kb * 4]        = p0;
            *(f32x4*)&sp[(cl + 16) * 20 + kb * 4] = p1;
            if (has2) *(f32x4*)&sp[(cl + 32) * 20 + kb * 4] = p2;

            // prefetch next group's hs (hidden under box/MFMA)
            if (g < 3) {
                const int cbn = (g + 1) * 16 + kb * 4;
                #pragma unroll
                for (int c4 = 0; c4 < 4; ++c4) {
                    const float* hp = hsb + (size_t)(cbn + c4) * HW;
                    h0[c4] = hp[gof0]; h1[c4] = hp[gof1];
                    h2[c4] = has2 ? hp[gof2] : 0.f;
                    hcv[c4] = hp[gc];
                }
            }

            // 3x3 box-sum of p (wave-private LDS; compiler inserts lgkm waits)
            f32x4 cr = (f32x4){0.f, 0.f, 0.f, 0.f};
            #pragma unroll
            for (int dy = 0; dy < 3; ++dy)
                #pragma unroll
                for (int dx = 0; dx < 3; ++dx)
                    cr += *(const f32x4*)&sp[((pr + dy) * 10 + (pc + dx)) * 20 + kb * 4];

            // sigmoid gate; B-fragment built directly in registers (no transpose!)
            float av[4];
            #pragma unroll
            for (int c4 = 0; c4 < 4; ++c4)
                av[c4] = __builtin_amdgcn_rcpf(
                    1.0f + __builtin_amdgcn_exp2f(cr[c4] * -1.44269504088896f)) * hgate[c4];
            union { unsigned u[4]; bf16x8 v; } bfr;
            bfr.u[0] = cvt_pk_bf16(av[0], av[1]);
            bfr.u[1] = cvt_pk_bf16(av[2], av[3]);
            bfr.u[2] = cvt_pk_bf16(hgate[0], hgate[1]);
            bfr.u[3] = cvt_pk_bf16(hgate[2], hgate[3]);

            #pragma unroll
            for (int mt = 0; mt < 4; ++mt) {
                const bf16x8 af = *(const bf16x8*)&s_w[(mt*16 + cl) * 136 + g*32 + kb*8];
                acc[mt] = __builtin_amdgcn_mfma_f32_16x16x32_bf16(af, bfr.v, acc[mt], 0, 0, 0);
            }
        }

        // store strip output (+bias): C/D col=cl -> pixel, row=kb*4+r -> out-ch
        float* const ob = out + (size_t)b * CC * HW;
        #pragma unroll
        for (int mt = 0; mt < 4; ++mt) {
            #pragma unroll
            for (int r = 0; r < 4; ++r) {
                const int o = mt * 16 + kb * 4 + r;
                ob[(size_t)o * HW + gc] = acc[mt][r] + b_fuse[o];
            }
        }
    }
}

extern "C" void kernel_launch(void* const* d_in, const int* in_sizes, int n_in,
                              void* d_out, int out_size, void* d_ws, size_t ws_size,
                              hipStream_t stream) {
    const float* hs      = (const float*)d_in[0];
    const float* refLR   = (const float*)d_in[1];
    const float* w_first = (const float*)d_in[2];
    const float* b_first = (const float*)d_in[3];
    const float* w_fuse  = (const float*)d_in[4];
    const float* b_fuse  = (const float*)d_in[5];
    float* out = (float*)d_out;

    corr_regB_kernel<<<dim3(2048), dim3(256), 0, stream>>>(hs, refLR, w_first, b_first,
                                                           w_fuse, b_fuse, out);
}

// Round 5
// 190.081 us; speedup vs baseline: 2.6881x; 2.6881x over previous
//
#include <hip/hip_runtime.h>

// B=8, C=64, H=256, W=256
#define BB 8
#define CC 64
#define HH 256
#define WW 256
#define HW (HH*WW)

typedef __attribute__((ext_vector_type(8))) short bf16x8;
typedef __attribute__((ext_vector_type(4))) float f32x4;

__device__ __forceinline__ int reflect_idx(int v, int n) {
    if (v < 0) v = -v;
    if (v >= n) v = 2*n - 2 - v;
    return v;
}

// f32 -> bf16 (RNE) raw bits
__device__ __forceinline__ short f2bf(float f) {
    union { float f; unsigned u; } x; x.f = f;
    unsigned r = (x.u + 0x7fffu + ((x.u >> 16) & 1u)) >> 16;
    return (short)r;
}

__device__ __forceinline__ unsigned cvt_pk_bf16(float lo, float hi) {
    unsigned r;
    asm("v_cvt_pk_bf16_f32 %0, %1, %2" : "=v"(r) : "v"(lo), "v"(hi));
    return r;
}

__global__ __launch_bounds__(256, 4)
void corr_v5_kernel(const float* __restrict__ hs,
                    const float* __restrict__ refLR,
                    const float* __restrict__ w_first,
                    const float* __restrict__ b_first,
                    const float* __restrict__ w_fuse,
                    const float* __restrict__ b_fuse,
                    float* __restrict__ out)
{
    // s_w: bf16 w_fuse, quad-interleaved k-order (k' = g*32 + q*8 + j):
    //      j<4 -> att col (g*16+q*4+j), j>=4 -> hs col (64+g*16+q*4+j-4)
    __shared__ short s_w[64 * 136];      // 17408 B, row 272B -> 8-optimal b128
    __shared__ float s_bf[64];           // 256 B bias
    __shared__ float s_p[4][60 * 20];    // 4*4800 B wave-private p=[pos 60][16ch pad20]
                                         // total 36864 B -> 4 blocks/CU

    const int t = threadIdx.x;
    const int wv = t >> 6, lane = t & 63;
    const int cl = lane & 15, kb = lane >> 4;   // pixel-in-strip, channel-quad
    const int pr = cl >> 3, pc = cl & 7;        // row/col within 2x8 strip

    // XCD swizzle: each XCD owns one batch image; x-adjacent blocks adjacent in XCD
    const int d = (int)blockIdx.x;
    const int lid = (d & 7) * 512 + (d >> 3);
    const int b = lid >> 9;
    const int r9 = lid & 511;
    const int by = r9 >> 4, bx = r9 & 15;       // by: 32 y-tiles of 8, bx: 16 x-tiles of 16

    // ---- stage weights + bias ----
    #pragma unroll
    for (int rep = 0; rep < 32; ++rep) {
        int idx = t + rep * 256;                // m*128 + k'
        int m = idx >> 7, k = idx & 127;
        int g = k >> 5, r = k & 31, q = r >> 3, j = r & 7;
        int col = (j < 4) ? (g*16 + q*4 + j) : (64 + g*16 + q*4 + j - 4);
        s_w[m * 136 + k] = f2bf(w_fuse[m * 128 + col]);
    }
    if (t < 64) s_bf[t] = b_fuse[t];
    __syncthreads();   // only block barrier

    // ---- wave tile: 4x8 pixels (2 strips of 2x8) ----
    const int y0 = by * 8 + (wv >> 1) * 4;
    const int x0 = bx * 16 + (wv & 1) * 8;

    // halo: 6 rows x 10 cols = 60 positions; lane<60 owns one
    const bool own = lane < 60;
    const int hl = own ? lane : 0;
    const int hy = hl / 10, hx = hl % 10;
    const int gof = reflect_idx(y0 - 1 + hy, HH) * WW + reflect_idx(x0 - 1 + hx, WW);
    const int spw = hl * 20;                    // LDS write base (words)

    // refLR halo values: loaded ONCE (lane = position -> coalesced per plane)
    const float* rbase = refLR + (size_t)b * 9 * HW;
    float rin[9];
    #pragma unroll
    for (int j = 0; j < 9; ++j) rin[j] = rbase[(size_t)j * HW + gof];

    const float* hsb = hs + (size_t)b * CC * HW;
    const int gc0 = (y0 + pr) * WW + (x0 + pc); // strip-0 center offset

    // prefetch group-0 hs halo values (one plane per instruction, coalesced)
    float h[16];
    #pragma unroll
    for (int i = 0; i < 16; ++i) h[i] = hsb[(size_t)i * HW + gof];

    f32x4 acc[2][4];
    #pragma unroll
    for (int nt = 0; nt < 2; ++nt)
        #pragma unroll
        for (int mt = 0; mt < 4; ++mt) acc[nt][mt] = (f32x4){0.f, 0.f, 0.f, 0.f};

    float* const sp = s_p[wv];

    #pragma unroll 1
    for (int g = 0; g < 4; ++g) {
        // ---- conv phase (lane = halo position): ref 1x1 conv + leaky, p = hs*ref ----
        #pragma unroll
        for (int q = 0; q < 4; ++q) {
            f32x4 pq;
            #pragma unroll
            for (int c4 = 0; c4 < 4; ++c4) {
                const int c = g * 16 + q * 4 + c4;
                float v = b_first[c];                       // wave-uniform (s_load)
                #pragma unroll
                for (int j = 0; j < 9; ++j)
                    v = fmaf(w_first[c * 9 + j], rin[j], v);
                v = v > 0.f ? v : 0.1f * v;
                pq[c4] = h[q * 4 + c4] * v;
            }
            if (own) *(f32x4*)&sp[spw + q * 4] = pq;
        }

        // prefetch next group's hs halo (hidden under pixel phase)
        if (g < 3) {
            #pragma unroll
            for (int i = 0; i < 16; ++i)
                h[i] = hsb[(size_t)((g + 1) * 16 + i) * HW + gof];
        }

        // center hs values for gating (L1/L2-hot: same lines as halo loads)
        float cen[2][4];
        #pragma unroll
        for (int nt = 0; nt < 2; ++nt)
            #pragma unroll
            for (int c4 = 0; c4 < 4; ++c4)
                cen[nt][c4] = hsb[(size_t)(g * 16 + kb * 4 + c4) * HW + gc0 + nt * 2 * WW];

        // ---- pixel phase (lane = (cl,kb)): box-sum, sigmoid, MFMA ----
        #pragma unroll
        for (int nt = 0; nt < 2; ++nt) {
            f32x4 cr = (f32x4){0.f, 0.f, 0.f, 0.f};
            #pragma unroll
            for (int dy = 0; dy < 3; ++dy)
                #pragma unroll
                for (int dx = 0; dx < 3; ++dx)
                    cr += *(const f32x4*)&sp[((nt*2 + pr + dy) * 10 + (pc + dx)) * 20 + kb * 4];

            float av[4];
            #pragma unroll
            for (int c4 = 0; c4 < 4; ++c4)
                av[c4] = __builtin_amdgcn_rcpf(
                    1.0f + __builtin_amdgcn_exp2f(cr[c4] * -1.44269504088896f)) * cen[nt][c4];

            union { unsigned u[4]; bf16x8 v; } bfr;
            bfr.u[0] = cvt_pk_bf16(av[0], av[1]);
            bfr.u[1] = cvt_pk_bf16(av[2], av[3]);
            bfr.u[2] = cvt_pk_bf16(cen[nt][0], cen[nt][1]);
            bfr.u[3] = cvt_pk_bf16(cen[nt][2], cen[nt][3]);

            #pragma unroll
            for (int mt = 0; mt < 4; ++mt) {
                const bf16x8 af = *(const bf16x8*)&s_w[(mt*16 + cl) * 136 + g*32 + kb*8];
                acc[nt][mt] = __builtin_amdgcn_mfma_f32_16x16x32_bf16(af, bfr.v, acc[nt][mt], 0, 0, 0);
            }
        }
    }

    // ---- bulk epilogue: out[b][o][y][x] = acc + bias ----
    float* const ob = out + (size_t)b * CC * HW;
    #pragma unroll
    for (int mt = 0; mt < 4; ++mt) {
        #pragma unroll
        for (int r = 0; r < 4; ++r) {
            const int o = mt * 16 + kb * 4 + r;
            const float bias = s_bf[o];
            #pragma unroll
            for (int nt = 0; nt < 2; ++nt)
                ob[(size_t)o * HW + gc0 + nt * 2 * WW] = acc[nt][mt][r] + bias;
        }
    }
}

extern "C" void kernel_launch(void* const* d_in, const int* in_sizes, int n_in,
                              void* d_out, int out_size, void* d_ws, size_t ws_size,
                              hipStream_t stream) {
    const float* hs      = (const float*)d_in[0];
    const float* refLR   = (const float*)d_in[1];
    const float* w_first = (const float*)d_in[2];
    const float* b_first = (const float*)d_in[3];
    const float* w_fuse  = (const float*)d_in[4];
    const float* b_fuse  = (const float*)d_in[5];
    float* out = (float*)d_out;

    corr_v5_kernel<<<dim3(4096), dim3(256), 0, stream>>>(hs, refLR, w_first, b_first,
                                                         w_fuse, b_fuse, out);
}